// Round 2
// baseline (9968.271 us; speedup 1.0000x reference)
//
#include <hip/hip_runtime.h>
#include <math.h>

#define BS 4
#define HH 480
#define WW 640
#define NC 16
#define CHN 20
#define MM 480
#define VRD 100
#define ZHD 80
#define MINZ 9
#define MAXZ 49
#define ZC 40            // z-slices kept for channel grid ([MINZ, MAXZ))

// d_out float offsets
#define OFF0 0            // fp_map_pred (4*1*100*100 = 40000)
#define OFF1 40000        // map_pred (4*20*480*480 = 18432000)  [scratch: V0/Vc early, rotated mid]
#define OFF2 18472000     // current_poses (12)
#define OFF3 18472012     // current_poses (12)
#define OFF4 18472024     // translated (18432000)
#define OFFM 28840000     // scratch maps (4*18*100*100 = 720000), inside translated slot (dead until translate)

__device__ __forceinline__ void pose_params(const float* __restrict__ pose_obs,
                                            const float* __restrict__ poses_last,
                                            int b, float& ct, float& st,
                                            float& stx, float& sty) {
    const float DEG = 57.29577951308232f;
    float o  = poses_last[b*3+2] / DEG;
    float so = sinf(o), co = cosf(o);
    float yy = poses_last[b*3+1] + pose_obs[b*3+0]*so + pose_obs[b*3+1]*co;
    float xx = poses_last[b*3+0] + pose_obs[b*3+0]*co - pose_obs[b*3+1]*so;
    float tt = poses_last[b*3+2] + pose_obs[b*3+2]*DEG;
    tt = fmodf(tt - 180.0f, 360.0f) + 180.0f;
    tt = fmodf(tt + 180.0f, 360.0f) - 180.0f;
    stx = -((xx*100.0f/5.0f) - 240.0f) / 240.0f;
    sty = -((yy*100.0f/5.0f) - 240.0f) / 240.0f;
    float t = (90.0f - tt) * 0.017453292519943295f;
    ct = cosf(t); st = sinf(t);
}

__global__ __launch_bounds__(64) void pose_kernel(const float* __restrict__ pose_obs,
                                                  const float* __restrict__ poses_last,
                                                  float* __restrict__ out) {
    int b = threadIdx.x;
    if (b >= BS) return;
    const float DEG = 57.29577951308232f;
    float o  = poses_last[b*3+2] / DEG;
    float so = sinf(o), co = cosf(o);
    float yy = poses_last[b*3+1] + pose_obs[b*3+0]*so + pose_obs[b*3+1]*co;
    float xx = poses_last[b*3+0] + pose_obs[b*3+0]*co - pose_obs[b*3+1]*so;
    float tt = poses_last[b*3+2] + pose_obs[b*3+2]*DEG;
    tt = fmodf(tt - 180.0f, 360.0f) + 180.0f;
    tt = fmodf(tt + 180.0f, 360.0f) - 180.0f;
    out[OFF2 + b*3+0] = xx; out[OFF2 + b*3+1] = yy; out[OFF2 + b*3+2] = tt;
    out[OFF3 + b*3+0] = xx; out[OFF3 + b*3+1] = yy; out[OFF3 + b*3+2] = tt;
}

// V0 layout: [b][x][y][z80]        (column-contiguous)
// Vc layout: [b][x][y][z40][c16]   (channel group = 64B aligned block -> 1 cache line per corner)
__global__ __launch_bounds__(256) void splat_kernel(const float* __restrict__ obs,
                                                    const float* __restrict__ view_angles,
                                                    float* __restrict__ V0,
                                                    float* __restrict__ Vc,
                                                    float foc) {
    int idx = blockIdx.x * blockDim.x + threadIdx.x;
    if (idx >= BS * HH * WW) return;
    int b   = idx / (HH * WW);
    int rem = idx % (HH * WW);
    int h   = rem / WW;
    int w   = rem % WW;
    const float* ob = obs + (size_t)b * CHN * HH * WW;
    float depth = ob[(size_t)3 * HH * WW + rem];
    float gx = (float)w;
    float gz = (float)(HH - 1 - h);
    float Xp = (gx - 319.5f) * depth / foc;
    float Zp = (gz - 239.5f) * depth / foc;
    float a  = view_angles[b] * 0.017453292519943295f;
    float ca = cosf(a), sa = sinf(a);
    float Yv = ca * depth - sa * Zp;
    float Zv = sa * depth + ca * Zp + 155.0f;
    float Xv = Xp + 250.0f;
    float xs = (Xv / 5.0f - 50.0f) / 100.0f * 2.0f;
    float ys = (Yv / 5.0f - 50.0f) / 100.0f * 2.0f;
    float zs = (Zv / 5.0f - 32.0f) / 80.0f * 2.0f;
    float px = xs * 50.0f + 50.0f;
    float py = ys * 50.0f + 50.0f;
    float pz = zs * 40.0f + 40.0f;

    float wx[2], wy[2], wz[2];
    int ixi[2], iyi[2], izi[2];
    {
        float fl = floorf(px);
        #pragma unroll
        for (int i = 0; i < 2; i++) {
            float p = fl + (float)i;
            bool s = (p > 0.0f) && (p < 100.0f);
            wx[i] = s ? (1.0f - fabsf(px - p)) : 0.0f;
            ixi[i] = s ? (int)p : 0;
        }
        fl = floorf(py);
        #pragma unroll
        for (int i = 0; i < 2; i++) {
            float p = fl + (float)i;
            bool s = (p > 0.0f) && (p < 100.0f);
            wy[i] = s ? (1.0f - fabsf(py - p)) : 0.0f;
            iyi[i] = s ? (int)p : 0;
        }
        fl = floorf(pz);
        #pragma unroll
        for (int i = 0; i < 2; i++) {
            float p = fl + (float)i;
            bool s = (p > 0.0f) && (p < 80.0f);
            wz[i] = s ? (1.0f - fabsf(pz - p)) : 0.0f;
            izi[i] = s ? (int)p : 0;
        }
    }

    float semv[NC];
    #pragma unroll
    for (int c = 0; c < NC; c++)
        semv[c] = ob[(size_t)(4 + c) * HH * WW + rem];

    #pragma unroll
    for (int i = 0; i < 2; i++) {
        if (wx[i] == 0.0f) continue;
        #pragma unroll
        for (int j = 0; j < 2; j++) {
            float wxy = wx[i] * wy[j];
            if (wxy == 0.0f) continue;
            size_t col = (size_t)(b * VRD + ixi[i]) * VRD + iyi[j];
            #pragma unroll
            for (int k = 0; k < 2; k++) {
                float wgt = wxy * wz[k];
                if (wgt == 0.0f) continue;
                int vz = izi[k];
                atomicAdd(V0 + col * ZHD + vz, wgt);
                if (vz >= MINZ && vz < MAXZ) {
                    int zr = vz - MINZ;
                    float* p0 = Vc + (col * ZC + zr) * NC;   // 16 contiguous floats, 64B aligned
                    #pragma unroll
                    for (int c = 0; c < NC; c++)
                        atomicAdd(p0 + c, wgt * semv[c]);
                }
            }
        }
    }
}

// Threads [0, BS*VRD*VRD*16): per (col, c) channel reduction (lanes contiguous over c -> coalesced 64B groups)
// Threads [BS*VRD*VRD*16, +BS*VRD*VRD): per col V0 reduction (contiguous 320B streams)
__global__ __launch_bounds__(256) void reduce_kernel(const float* __restrict__ V0,
                                                     const float* __restrict__ Vc,
                                                     float* __restrict__ maps,
                                                     float* __restrict__ out0) {
    const int NCOL = BS * VRD * VRD;
    int idx = blockIdx.x * blockDim.x + threadIdx.x;
    if (idx < NCOL * NC) {
        int col = idx >> 4;        // (b*100 + x)*100 + y
        int c   = idx & 15;
        int b   = col / (VRD * VRD);
        int rr  = col % (VRD * VRD);
        int xj  = rr / VRD;
        int yi  = rr % VRD;
        const float* q = Vc + (size_t)col * ZC * NC + c;
        float s = 0.0f;
        #pragma unroll 4
        for (int z = 0; z < ZC; z++) s += rintf(q[(size_t)z * NC]);
        float v = fminf(fmaxf(s * 0.2f, 0.0f), 1.0f);
        maps[((size_t)b * 18 + (c + 2)) * VRD * VRD + yi * VRD + xj] = v;
    } else if (idx < NCOL * NC + NCOL) {
        int col = idx - NCOL * NC;
        int b   = col / (VRD * VRD);
        int rr  = col % (VRD * VRD);
        int xj  = rr / VRD;
        int yi  = rr % VRD;
        const float* p = V0 + (size_t)col * ZHD;
        float s_all = 0.0f, s_agg = 0.0f;
        #pragma unroll 4
        for (int z = 0; z < ZHD; z++) {
            float r = rintf(p[z]);
            s_all += r;
            if (z >= MINZ && z < MAXZ) s_agg += r;
        }
        float fm = fminf(fmaxf(s_agg, 0.0f), 1.0f);
        float fe = fminf(fmaxf(s_all, 0.0f), 1.0f);
        maps[((size_t)b * 18 + 0) * VRD * VRD + yi * VRD + xj] = fm;
        maps[((size_t)b * 18 + 1) * VRD * VRD + yi * VRD + xj] = fe;
        out0[(size_t)b * VRD * VRD + yi * VRD + xj] = fm;
    }
}

__global__ __launch_bounds__(256) void rotate_kernel(const float* __restrict__ maps,
                                                     const float* __restrict__ pose_obs,
                                                     const float* __restrict__ poses_last,
                                                     float* __restrict__ rot) {
    int idx = blockIdx.x * blockDim.x + threadIdx.x;
    if (idx >= BS * MM * MM) return;
    int b   = idx / (MM * MM);
    int rem = idx % (MM * MM);
    int y   = rem / MM;
    int x   = rem % MM;
    float ct, st, stx, sty;
    pose_params(pose_obs, poses_last, b, ct, st, stx, sty);
    float Xg = -1.0f + (float)x * (2.0f / 479.0f);
    float Yg = -1.0f + (float)y * (2.0f / 479.0f);
    float gx = ct * Xg - st * Yg;
    float gy = st * Xg + ct * Yg;
    float xf = (gx + 1.0f) * 0.5f * 479.0f;
    float yf = (gy + 1.0f) * 0.5f * 479.0f;
    float x0 = floorf(xf), y0 = floorf(yf);
    float fx = xf - x0, fy = yf - y0;
    float cw[4] = {(1.0f - fx) * (1.0f - fy), fx * (1.0f - fy),
                   (1.0f - fx) * fy,          fx * fy};
    float cx[4] = {x0, x0 + 1.0f, x0, x0 + 1.0f};
    float cy[4] = {y0, y0, y0 + 1.0f, y0 + 1.0f};
    float acc[18];
    #pragma unroll
    for (int m = 0; m < 18; m++) acc[m] = 0.0f;
    #pragma unroll
    for (int k = 0; k < 4; k++) {
        float fxk = cx[k], fyk = cy[k];
        if (!(fxk >= 0.0f && fxk <= 479.0f && fyk >= 0.0f && fyk <= 479.0f)) continue;
        int ix = (int)fxk, iy = (int)fyk;
        if (iy < 240 || iy >= 340 || ix < 190 || ix >= 290) continue;
        int mi = iy - 240, mj = ix - 190;
        float w = cw[k];
        const float* mp = maps + (size_t)b * 18 * VRD * VRD + mi * VRD + mj;
        #pragma unroll
        for (int m = 0; m < 18; m++) acc[m] += w * mp[(size_t)m * VRD * VRD];
    }
    size_t obase = ((size_t)b * CHN) * MM * MM + (size_t)y * MM + x;
    rot[obase + (size_t)0 * MM * MM] = acc[0];
    rot[obase + (size_t)1 * MM * MM] = acc[1];
    rot[obase + (size_t)2 * MM * MM] = 0.0f;
    rot[obase + (size_t)3 * MM * MM] = 0.0f;
    #pragma unroll
    for (int m = 2; m < 18; m++)
        rot[obase + (size_t)(m + 2) * MM * MM] = acc[m];
}

__global__ __launch_bounds__(256) void translate_kernel(const float* __restrict__ rot,
                                                        const float* __restrict__ pose_obs,
                                                        const float* __restrict__ poses_last,
                                                        float* __restrict__ tr) {
    int idx = blockIdx.x * blockDim.x + threadIdx.x;
    if (idx >= BS * MM * MM) return;
    int b   = idx / (MM * MM);
    int rem = idx % (MM * MM);
    int y   = rem / MM;
    int x   = rem % MM;
    float ct, st, stx, sty;
    pose_params(pose_obs, poses_last, b, ct, st, stx, sty);
    float Xg = -1.0f + (float)x * (2.0f / 479.0f);
    float Yg = -1.0f + (float)y * (2.0f / 479.0f);
    float xf = (Xg + stx + 1.0f) * 0.5f * 479.0f;
    float yf = (Yg + sty + 1.0f) * 0.5f * 479.0f;
    float x0 = floorf(xf), y0 = floorf(yf);
    float fx = xf - x0, fy = yf - y0;
    float cw[4] = {(1.0f - fx) * (1.0f - fy), fx * (1.0f - fy),
                   (1.0f - fx) * fy,          fx * fy};
    float cxs[4] = {x0, x0 + 1.0f, x0, x0 + 1.0f};
    float cys[4] = {y0, y0, y0 + 1.0f, y0 + 1.0f};
    bool vk[4]; int offk[4];
    #pragma unroll
    for (int k = 0; k < 4; k++) {
        vk[k] = (cxs[k] >= 0.0f && cxs[k] <= 479.0f && cys[k] >= 0.0f && cys[k] <= 479.0f);
        offk[k] = vk[k] ? ((int)cys[k] * MM + (int)cxs[k]) : 0;
    }
    #pragma unroll
    for (int c = 0; c < CHN; c++) {
        const float* rp = rot + ((size_t)b * CHN + c) * MM * MM;
        float v = 0.0f;
        #pragma unroll
        for (int k = 0; k < 4; k++)
            if (vk[k]) v += cw[k] * rp[offk[k]];
        tr[((size_t)b * CHN + c) * MM * MM + (size_t)y * MM + x] = v;
    }
}

__global__ __launch_bounds__(256) void max_kernel(const float* __restrict__ maps_last,
                                                  const float* __restrict__ tr,
                                                  float* __restrict__ mp) {
    int i = blockIdx.x * blockDim.x + threadIdx.x;
    int n4 = BS * CHN * MM * MM / 4;
    if (i >= n4) return;
    float4 a = ((const float4*)maps_last)[i];
    float4 t = ((const float4*)tr)[i];
    float4 r;
    r.x = fmaxf(a.x, t.x);
    r.y = fmaxf(a.y, t.y);
    r.z = fmaxf(a.z, t.z);
    r.w = fmaxf(a.w, t.w);
    ((float4*)mp)[i] = r;
}

extern "C" void kernel_launch(void* const* d_in, const int* in_sizes, int n_in,
                              void* d_out, int out_size, void* d_ws, size_t ws_size,
                              hipStream_t stream) {
    const float* obs         = (const float*)d_in[0];
    const float* pose_obs    = (const float*)d_in[1];
    const float* maps_last   = (const float*)d_in[2];
    const float* poses_last  = (const float*)d_in[3];
    const float* view_angles = (const float*)d_in[4];
    float* out = (float*)d_out;

    // scratch (inside d_out, regions dead until later stages):
    float* V0   = out + OFF1;                              // 4*100*100*80    = 3,200,000
    float* Vc   = V0 + (size_t)BS * VRD * VRD * ZHD;       // 4*100*100*40*16 = 25,600,000
    float* maps = out + OFFM;                              // 4*18*100*100    = 720,000

    // zero voxel grids (115.2 MB)
    hipMemsetAsync(V0, 0, (size_t)(BS * VRD * VRD * ZHD + (size_t)BS * VRD * VRD * ZC * NC)
                          * sizeof(float), stream);

    const float foc = (float)(320.0 / tan(39.5 * M_PI / 180.0));

    int npix = BS * HH * WW;
    splat_kernel<<<(npix + 255) / 256, 256, 0, stream>>>(obs, view_angles, V0, Vc, foc);

    int nred = BS * VRD * VRD * (NC + 1);
    reduce_kernel<<<(nred + 255) / 256, 256, 0, stream>>>(V0, Vc, maps, out + OFF0);

    pose_kernel<<<1, 64, 0, stream>>>(pose_obs, poses_last, out);

    int nmap = BS * MM * MM;
    rotate_kernel<<<(nmap + 255) / 256, 256, 0, stream>>>(maps, pose_obs, poses_last,
                                                          out + OFF1);
    translate_kernel<<<(nmap + 255) / 256, 256, 0, stream>>>(out + OFF1, pose_obs,
                                                             poses_last, out + OFF4);
    int n4 = BS * CHN * MM * MM / 4;
    max_kernel<<<(n4 + 255) / 256, 256, 0, stream>>>(maps_last, out + OFF4, out + OFF1);
}

// Round 3
// 7336.237 us; speedup vs baseline: 1.3588x; 1.3588x over previous
//
#include <hip/hip_runtime.h>
#include <math.h>

#define BS 4
#define HH 480
#define WW 640
#define NC 16
#define CHN 20
#define MM 480
#define VRD 100
#define ZHD 80
#define MINZ 9
#define MAXZ 49
#define ZC 40

// d_out float offsets
#define OFF0 0            // fp_map_pred (4*1*100*100 = 40000)
#define OFF1 40000        // map_pred (4*20*480*480 = 18432000)  [scratch: V0/Vc early, rotated mid]
#define OFF2 18472000     // current_poses (12)
#define OFF3 18472012     // current_poses (12)
#define OFF4 18472024     // translated (18432000)
#define OFFM 28840000     // scratch maps (4*18*100*100 = 720000), inside translated slot (dead until translate)

__device__ __forceinline__ void pose_params(const float* __restrict__ pose_obs,
                                            const float* __restrict__ poses_last,
                                            int b, float& ct, float& st,
                                            float& stx, float& sty) {
    const float DEG = 57.29577951308232f;
    float o  = poses_last[b*3+2] / DEG;
    float so = sinf(o), co = cosf(o);
    float yy = poses_last[b*3+1] + pose_obs[b*3+0]*so + pose_obs[b*3+1]*co;
    float xx = poses_last[b*3+0] + pose_obs[b*3+0]*co - pose_obs[b*3+1]*so;
    float tt = poses_last[b*3+2] + pose_obs[b*3+2]*DEG;
    tt = fmodf(tt - 180.0f, 360.0f) + 180.0f;
    tt = fmodf(tt + 180.0f, 360.0f) - 180.0f;
    stx = -((xx*100.0f/5.0f) - 240.0f) / 240.0f;
    sty = -((yy*100.0f/5.0f) - 240.0f) / 240.0f;
    float t = (90.0f - tt) * 0.017453292519943295f;
    ct = cosf(t); st = sinf(t);
}

__global__ __launch_bounds__(64) void pose_kernel(const float* __restrict__ pose_obs,
                                                  const float* __restrict__ poses_last,
                                                  float* __restrict__ out) {
    int b = threadIdx.x;
    if (b >= BS) return;
    const float DEG = 57.29577951308232f;
    float o  = poses_last[b*3+2] / DEG;
    float so = sinf(o), co = cosf(o);
    float yy = poses_last[b*3+1] + pose_obs[b*3+0]*so + pose_obs[b*3+1]*co;
    float xx = poses_last[b*3+0] + pose_obs[b*3+0]*co - pose_obs[b*3+1]*so;
    float tt = poses_last[b*3+2] + pose_obs[b*3+2]*DEG;
    tt = fmodf(tt - 180.0f, 360.0f) + 180.0f;
    tt = fmodf(tt + 180.0f, 360.0f) - 180.0f;
    out[OFF2 + b*3+0] = xx; out[OFF2 + b*3+1] = yy; out[OFF2 + b*3+2] = tt;
    out[OFF3 + b*3+0] = xx; out[OFF3 + b*3+1] = yy; out[OFF3 + b*3+2] = tt;
}

// V0 layout: [b][x][y][z80]        (column-contiguous)
// Vc layout: [b][c][x][y][z40]     (channels on separate lines -> spread across TCC channels)
__global__ __launch_bounds__(256) void splat_kernel(const float* __restrict__ obs,
                                                    const float* __restrict__ view_angles,
                                                    float* __restrict__ V0,
                                                    float* __restrict__ Vc,
                                                    float foc) {
    int idx = blockIdx.x * blockDim.x + threadIdx.x;
    if (idx >= BS * HH * WW) return;
    int b   = idx / (HH * WW);
    int rem = idx % (HH * WW);
    int h   = rem / WW;
    int w   = rem % WW;
    const float* ob = obs + (size_t)b * CHN * HH * WW;
    float depth = ob[(size_t)3 * HH * WW + rem];
    float gx = (float)w;
    float gz = (float)(HH - 1 - h);
    float Xp = (gx - 319.5f) * depth / foc;
    float Zp = (gz - 239.5f) * depth / foc;
    float a  = view_angles[b] * 0.017453292519943295f;
    float ca = cosf(a), sa = sinf(a);
    float Yv = ca * depth - sa * Zp;
    float Zv = sa * depth + ca * Zp + 155.0f;
    float Xv = Xp + 250.0f;
    float xs = (Xv / 5.0f - 50.0f) / 100.0f * 2.0f;
    float ys = (Yv / 5.0f - 50.0f) / 100.0f * 2.0f;
    float zs = (Zv / 5.0f - 32.0f) / 80.0f * 2.0f;
    float px = xs * 50.0f + 50.0f;
    float py = ys * 50.0f + 50.0f;
    float pz = zs * 40.0f + 40.0f;

    float wx[2], wy[2], wz[2];
    int ixi[2], iyi[2], izi[2];
    {
        float fl = floorf(px);
        #pragma unroll
        for (int i = 0; i < 2; i++) {
            float p = fl + (float)i;
            bool s = (p > 0.0f) && (p < 100.0f);
            wx[i] = s ? (1.0f - fabsf(px - p)) : 0.0f;
            ixi[i] = s ? (int)p : 0;
        }
        fl = floorf(py);
        #pragma unroll
        for (int i = 0; i < 2; i++) {
            float p = fl + (float)i;
            bool s = (p > 0.0f) && (p < 100.0f);
            wy[i] = s ? (1.0f - fabsf(py - p)) : 0.0f;
            iyi[i] = s ? (int)p : 0;
        }
        fl = floorf(pz);
        #pragma unroll
        for (int i = 0; i < 2; i++) {
            float p = fl + (float)i;
            bool s = (p > 0.0f) && (p < 80.0f);
            wz[i] = s ? (1.0f - fabsf(pz - p)) : 0.0f;
            izi[i] = s ? (int)p : 0;
        }
    }

    float semv[NC];
    #pragma unroll
    for (int c = 0; c < NC; c++)
        semv[c] = ob[(size_t)(4 + c) * HH * WW + rem];

    #pragma unroll
    for (int i = 0; i < 2; i++) {
        if (wx[i] == 0.0f) continue;
        #pragma unroll
        for (int j = 0; j < 2; j++) {
            float wxy = wx[i] * wy[j];
            if (wxy == 0.0f) continue;
            size_t col = (size_t)(b * VRD + ixi[i]) * VRD + iyi[j];
            size_t xy  = (size_t)(ixi[i] * VRD + iyi[j]);
            #pragma unroll
            for (int k = 0; k < 2; k++) {
                float wgt = wxy * wz[k];
                if (wgt == 0.0f) continue;
                int vz = izi[k];
                unsafeAtomicAdd(V0 + col * ZHD + vz, wgt);
                if (vz >= MINZ && vz < MAXZ) {
                    int zr = vz - MINZ;
                    float* p0 = Vc + (size_t)b * NC * VRD * VRD * ZC
                                   + xy * ZC + zr;
                    #pragma unroll
                    for (int c = 0; c < NC; c++)
                        unsafeAtomicAdd(p0 + (size_t)c * VRD * VRD * ZC, wgt * semv[c]);
                }
            }
        }
    }
}

__global__ __launch_bounds__(256) void reduce_kernel(const float* __restrict__ V0,
                                                     const float* __restrict__ Vc,
                                                     float* __restrict__ maps,
                                                     float* __restrict__ out0) {
    int idx = blockIdx.x * blockDim.x + threadIdx.x;
    if (idx >= BS * 17 * VRD * VRD) return;
    int b   = idx / (17 * VRD * VRD);
    int rem = idx % (17 * VRD * VRD);
    int c   = rem / (VRD * VRD);
    int rr  = rem % (VRD * VRD);
    int xj  = rr / VRD;
    int yi  = rr % VRD;
    if (c == 0) {
        const float* p = V0 + (size_t)((b * VRD + xj) * VRD + yi) * ZHD;
        float s_all = 0.0f, s_agg = 0.0f;
        #pragma unroll 4
        for (int z = 0; z < ZHD; z++) {
            float r = rintf(p[z]);
            s_all += r;
            if (z >= MINZ && z < MAXZ) s_agg += r;
        }
        float fm = fminf(fmaxf(s_agg, 0.0f), 1.0f);
        float fe = fminf(fmaxf(s_all, 0.0f), 1.0f);
        maps[((size_t)b * 18 + 0) * VRD * VRD + yi * VRD + xj] = fm;
        maps[((size_t)b * 18 + 1) * VRD * VRD + yi * VRD + xj] = fe;
        out0[(size_t)b * VRD * VRD + yi * VRD + xj] = fm;
    } else {
        const float* p = Vc + ((size_t)(b * NC + (c - 1)) * VRD * VRD
                               + (size_t)(xj * VRD + yi)) * ZC;
        float s = 0.0f;
        #pragma unroll 4
        for (int z = 0; z < ZC; z++) s += rintf(p[z]);
        float v = fminf(fmaxf(s * 0.2f, 0.0f), 1.0f);
        maps[((size_t)b * 18 + (c + 1)) * VRD * VRD + yi * VRD + xj] = v;
    }
}

__global__ __launch_bounds__(256) void rotate_kernel(const float* __restrict__ maps,
                                                     const float* __restrict__ pose_obs,
                                                     const float* __restrict__ poses_last,
                                                     float* __restrict__ rot) {
    int idx = blockIdx.x * blockDim.x + threadIdx.x;
    if (idx >= BS * MM * MM) return;
    int b   = idx / (MM * MM);
    int rem = idx % (MM * MM);
    int y   = rem / MM;
    int x   = rem % MM;
    float ct, st, stx, sty;
    pose_params(pose_obs, poses_last, b, ct, st, stx, sty);
    float Xg = -1.0f + (float)x * (2.0f / 479.0f);
    float Yg = -1.0f + (float)y * (2.0f / 479.0f);
    float gx = ct * Xg - st * Yg;
    float gy = st * Xg + ct * Yg;
    float xf = (gx + 1.0f) * 0.5f * 479.0f;
    float yf = (gy + 1.0f) * 0.5f * 479.0f;
    float x0 = floorf(xf), y0 = floorf(yf);
    float fx = xf - x0, fy = yf - y0;
    float cw[4] = {(1.0f - fx) * (1.0f - fy), fx * (1.0f - fy),
                   (1.0f - fx) * fy,          fx * fy};
    float cx[4] = {x0, x0 + 1.0f, x0, x0 + 1.0f};
    float cy[4] = {y0, y0, y0 + 1.0f, y0 + 1.0f};
    float acc[18];
    #pragma unroll
    for (int m = 0; m < 18; m++) acc[m] = 0.0f;
    #pragma unroll
    for (int k = 0; k < 4; k++) {
        float fxk = cx[k], fyk = cy[k];
        if (!(fxk >= 0.0f && fxk <= 479.0f && fyk >= 0.0f && fyk <= 479.0f)) continue;
        int ix = (int)fxk, iy = (int)fyk;
        if (iy < 240 || iy >= 340 || ix < 190 || ix >= 290) continue;
        int mi = iy - 240, mj = ix - 190;
        float w = cw[k];
        const float* mp = maps + (size_t)b * 18 * VRD * VRD + mi * VRD + mj;
        #pragma unroll
        for (int m = 0; m < 18; m++) acc[m] += w * mp[(size_t)m * VRD * VRD];
    }
    size_t obase = ((size_t)b * CHN) * MM * MM + (size_t)y * MM + x;
    rot[obase + (size_t)0 * MM * MM] = acc[0];
    rot[obase + (size_t)1 * MM * MM] = acc[1];
    rot[obase + (size_t)2 * MM * MM] = 0.0f;
    rot[obase + (size_t)3 * MM * MM] = 0.0f;
    #pragma unroll
    for (int m = 2; m < 18; m++)
        rot[obase + (size_t)(m + 2) * MM * MM] = acc[m];
}

__global__ __launch_bounds__(256) void translate_kernel(const float* __restrict__ rot,
                                                        const float* __restrict__ pose_obs,
                                                        const float* __restrict__ poses_last,
                                                        float* __restrict__ tr) {
    int idx = blockIdx.x * blockDim.x + threadIdx.x;
    if (idx >= BS * MM * MM) return;
    int b   = idx / (MM * MM);
    int rem = idx % (MM * MM);
    int y   = rem / MM;
    int x   = rem % MM;
    float ct, st, stx, sty;
    pose_params(pose_obs, poses_last, b, ct, st, stx, sty);
    float Xg = -1.0f + (float)x * (2.0f / 479.0f);
    float Yg = -1.0f + (float)y * (2.0f / 479.0f);
    float xf = (Xg + stx + 1.0f) * 0.5f * 479.0f;
    float yf = (Yg + sty + 1.0f) * 0.5f * 479.0f;
    float x0 = floorf(xf), y0 = floorf(yf);
    float fx = xf - x0, fy = yf - y0;
    float cw[4] = {(1.0f - fx) * (1.0f - fy), fx * (1.0f - fy),
                   (1.0f - fx) * fy,          fx * fy};
    float cxs[4] = {x0, x0 + 1.0f, x0, x0 + 1.0f};
    float cys[4] = {y0, y0, y0 + 1.0f, y0 + 1.0f};
    bool vk[4]; int offk[4];
    #pragma unroll
    for (int k = 0; k < 4; k++) {
        vk[k] = (cxs[k] >= 0.0f && cxs[k] <= 479.0f && cys[k] >= 0.0f && cys[k] <= 479.0f);
        offk[k] = vk[k] ? ((int)cys[k] * MM + (int)cxs[k]) : 0;
    }
    #pragma unroll
    for (int c = 0; c < CHN; c++) {
        const float* rp = rot + ((size_t)b * CHN + c) * MM * MM;
        float v = 0.0f;
        #pragma unroll
        for (int k = 0; k < 4; k++)
            if (vk[k]) v += cw[k] * rp[offk[k]];
        tr[((size_t)b * CHN + c) * MM * MM + (size_t)y * MM + x] = v;
    }
}

__global__ __launch_bounds__(256) void max_kernel(const float* __restrict__ maps_last,
                                                  const float* __restrict__ tr,
                                                  float* __restrict__ mp) {
    int i = blockIdx.x * blockDim.x + threadIdx.x;
    int n4 = BS * CHN * MM * MM / 4;
    if (i >= n4) return;
    float4 a = ((const float4*)maps_last)[i];
    float4 t = ((const float4*)tr)[i];
    float4 r;
    r.x = fmaxf(a.x, t.x);
    r.y = fmaxf(a.y, t.y);
    r.z = fmaxf(a.z, t.z);
    r.w = fmaxf(a.w, t.w);
    ((float4*)mp)[i] = r;
}

extern "C" void kernel_launch(void* const* d_in, const int* in_sizes, int n_in,
                              void* d_out, int out_size, void* d_ws, size_t ws_size,
                              hipStream_t stream) {
    const float* obs         = (const float*)d_in[0];
    const float* pose_obs    = (const float*)d_in[1];
    const float* maps_last   = (const float*)d_in[2];
    const float* poses_last  = (const float*)d_in[3];
    const float* view_angles = (const float*)d_in[4];
    float* out = (float*)d_out;

    // scratch (inside d_out, regions dead until later stages):
    float* V0   = out + OFF1;                              // 4*100*100*80    = 3,200,000
    float* Vc   = V0 + (size_t)BS * VRD * VRD * ZHD;       // 4*16*100*100*40 = 25,600,000
    float* maps = out + OFFM;                              // 4*18*100*100    = 720,000

    // zero voxel grids (115.2 MB)
    hipMemsetAsync(V0, 0, (size_t)(BS * VRD * VRD * ZHD + (size_t)BS * NC * VRD * VRD * ZC)
                          * sizeof(float), stream);

    const float foc = (float)(320.0 / tan(39.5 * M_PI / 180.0));

    int npix = BS * HH * WW;
    splat_kernel<<<(npix + 255) / 256, 256, 0, stream>>>(obs, view_angles, V0, Vc, foc);

    int nred = BS * 17 * VRD * VRD;
    reduce_kernel<<<(nred + 255) / 256, 256, 0, stream>>>(V0, Vc, maps, out + OFF0);

    pose_kernel<<<1, 64, 0, stream>>>(pose_obs, poses_last, out);

    int nmap = BS * MM * MM;
    rotate_kernel<<<(nmap + 255) / 256, 256, 0, stream>>>(maps, pose_obs, poses_last,
                                                          out + OFF1);
    translate_kernel<<<(nmap + 255) / 256, 256, 0, stream>>>(out + OFF1, pose_obs,
                                                             poses_last, out + OFF4);
    int n4 = BS * CHN * MM * MM / 4;
    max_kernel<<<(n4 + 255) / 256, 256, 0, stream>>>(maps_last, out + OFF4, out + OFF1);
}

// Round 4
// 1785.028 us; speedup vs baseline: 5.5844x; 4.1099x over previous
//
#include <hip/hip_runtime.h>
#include <math.h>

#define BS 4
#define HH 480
#define WW 640
#define NPX (HH * WW)          // 307200
#define NC 16
#define CHN 20
#define MM 480
#define VRD 100
#define ZHD 80
#define MINZ 9
#define MAXZ 49
#define CZ 8                    // z-slices per LDS chunk in slice_vc (5 chunks cover [9,49))
#define CAP 8192                // records per (b, y-bucket)

// d_out float offsets
#define OFF0 0                  // fp_map_pred (40000)
#define OFF1 40000              // map_pred (18432000)  [scratch: rotated mid]
#define OFF2 18472000           // current_poses (12)
#define OFF3 18472012           // current_poses (12)
#define OFF4 18472024           // translated (18432000)
#define OFFM 28840000           // maps scratch 4*18*100*100 = 720000 (inside OFF4, dead until translate)
#define OFFR 29560000           // records: 400*8192*2 floats = 6553600 (inside OFF4)
#define OFFC 36113600           // counters: 400*16 ints (inside OFF4)

__device__ __forceinline__ void pix2pos(int w, int h, float depth, float ca, float sa,
                                        float foc, float& px, float& py, float& pz) {
    float gx = (float)w;
    float gz = (float)(HH - 1 - h);
    float Xp = (gx - 319.5f) * depth / foc;
    float Zp = (gz - 239.5f) * depth / foc;
    float Yv = ca * depth - sa * Zp;
    float Zv = sa * depth + ca * Zp + 155.0f;
    float Xv = Xp + 250.0f;
    float xs = (Xv / 5.0f - 50.0f) / 100.0f * 2.0f;
    float ys = (Yv / 5.0f - 50.0f) / 100.0f * 2.0f;
    float zs = (Zv / 5.0f - 32.0f) / 80.0f * 2.0f;
    px = xs * 50.0f + 50.0f;
    py = ys * 50.0f + 50.0f;
    pz = zs * 40.0f + 40.0f;
}

__global__ __launch_bounds__(256) void bin_kernel(const float* __restrict__ obs,
                                                  const float* __restrict__ va,
                                                  int* __restrict__ cnt,
                                                  float2* __restrict__ rec,
                                                  float foc) {
    int idx = blockIdx.x * blockDim.x + threadIdx.x;
    if (idx >= BS * NPX) return;
    int b   = idx / NPX;
    int rem = idx % NPX;
    float depth = obs[((size_t)b * CHN + 3) * NPX + rem];
    int h = rem / WW, w = rem % WW;
    float a  = va[b] * 0.017453292519943295f;
    float ca = cosf(a), sa = sinf(a);
    float px, py, pz;
    pix2pos(w, h, depth, ca, sa, foc, px, py, pz);
    int f = (int)floorf(py);
    if (f < 0 || f > 99) return;
    int slot = atomicAdd(cnt + (b * VRD + f) * 16, 1);
    if (slot < CAP) {
        float2 r; r.x = __int_as_float(rem); r.y = depth;
        rec[(size_t)(b * VRD + f) * CAP + slot] = r;
    }
}

// one workgroup per (y-slice s, batch b): occupancy splat in LDS, fused z-reduction
__global__ __launch_bounds__(256) void slice_v0_kernel(const int* __restrict__ cnt,
                                                       const float2* __restrict__ rec,
                                                       const float* __restrict__ va,
                                                       float* __restrict__ maps,
                                                       float* __restrict__ out0,
                                                       float foc) {
    __shared__ float acc[VRD * ZHD];   // 32 KB
    int s = blockIdx.x;
    int b = blockIdx.y;
    int tid = threadIdx.x;
    for (int i = tid; i < VRD * ZHD; i += 256) acc[i] = 0.0f;
    __syncthreads();

    float a  = va[b] * 0.017453292519943295f;
    float ca = cosf(a), sa = sinf(a);
    int sm1 = (s > 0) ? s - 1 : 0;
    int n0 = (s > 0) ? min(cnt[(b * VRD + sm1) * 16], CAP) : 0;
    int n1 = min(cnt[(b * VRD + s) * 16], CAP);
    const float2* r0 = rec + (size_t)(b * VRD + sm1) * CAP;
    const float2* r1 = rec + (size_t)(b * VRD + s) * CAP;
    int N = n0 + n1;
    float fs = (float)s;

    for (int t = tid; t < N; t += 256) {
        float2 rv = (t < n0) ? r0[t] : r1[t - n0];
        int rem = __float_as_int(rv.x);
        float depth = rv.y;
        float px, py, pz;
        pix2pos(rem % WW, rem / WW, depth, ca, sa, foc, px, py, pz);
        float wy = 1.0f - fabsf(py - fs);
        if (s == 0 || wy <= 0.0f) continue;
        float fx = floorf(px), fz = floorf(pz);
        #pragma unroll
        for (int i = 0; i < 2; i++) {
            float cxp = fx + (float)i;
            if (!(cxp > 0.0f && cxp < 100.0f)) continue;
            float wxv = 1.0f - fabsf(px - cxp);
            int xi = (int)cxp;
            #pragma unroll
            for (int k = 0; k < 2; k++) {
                float czp = fz + (float)k;
                if (!(czp > 0.0f && czp < 80.0f)) continue;
                float wzv = 1.0f - fabsf(pz - czp);
                float wv = wy * wxv * wzv;
                if (wv != 0.0f) atomicAdd(&acc[xi * ZHD + (int)czp], wv);
            }
        }
    }
    __syncthreads();

    if (tid < VRD) {
        float s_all = 0.0f, s_agg = 0.0f;
        #pragma unroll 4
        for (int z = 0; z < ZHD; z++) {
            float r = rintf(acc[tid * ZHD + z]);
            s_all += r;
            if (z >= MINZ && z < MAXZ) s_agg += r;
        }
        float fm = fminf(fmaxf(s_agg, 0.0f), 1.0f);
        float fe = fminf(fmaxf(s_all, 0.0f), 1.0f);
        maps[((size_t)(b * 18 + 0) * VRD + s) * VRD + tid] = fm;
        maps[((size_t)(b * 18 + 1) * VRD + s) * VRD + tid] = fe;
        out0[((size_t)b * VRD + s) * VRD + tid] = fm;
    }
}

// one workgroup per (y-slice s, batch b): 16-channel splat in LDS over 5 z-chunks
__global__ __launch_bounds__(256) void slice_vc_kernel(const float* __restrict__ obs,
                                                       const int* __restrict__ cnt,
                                                       const float2* __restrict__ rec,
                                                       const float* __restrict__ va,
                                                       float* __restrict__ maps,
                                                       float foc) {
    __shared__ float chunkbuf[VRD * CZ * NC];  // 51.2 KB
    __shared__ float cat[VRD * NC];            // 6.4 KB
    int s = blockIdx.x;
    int b = blockIdx.y;
    int tid = threadIdx.x;
    for (int i = tid; i < VRD * NC; i += 256) cat[i] = 0.0f;

    float a  = va[b] * 0.017453292519943295f;
    float ca = cosf(a), sa = sinf(a);
    int sm1 = (s > 0) ? s - 1 : 0;
    int n0 = (s > 0) ? min(cnt[(b * VRD + sm1) * 16], CAP) : 0;
    int n1 = min(cnt[(b * VRD + s) * 16], CAP);
    const float2* r0 = rec + (size_t)(b * VRD + sm1) * CAP;
    const float2* r1 = rec + (size_t)(b * VRD + s) * CAP;
    int N = (s == 0) ? 0 : n0 + n1;
    float fs = (float)s;
    const float* semb = obs + ((size_t)b * CHN + 4) * NPX;

    for (int chunk = 0; chunk < 5; chunk++) {
        float zlo = (float)(MINZ + chunk * CZ);
        float zhi = zlo + (float)CZ;
        for (int i = tid; i < VRD * CZ * NC; i += 256) chunkbuf[i] = 0.0f;
        __syncthreads();

        for (int t = tid; t < N; t += 256) {
            float2 rv = (t < n0) ? r0[t] : r1[t - n0];
            int rem = __float_as_int(rv.x);
            float depth = rv.y;
            float px, py, pz;
            pix2pos(rem % WW, rem / WW, depth, ca, sa, foc, px, py, pz);
            float wy = 1.0f - fabsf(py - fs);
            if (wy <= 0.0f) continue;
            float fz = floorf(pz);
            float wz[2]; int zi[2]; bool zv[2];
            #pragma unroll
            for (int k = 0; k < 2; k++) {
                float czp = fz + (float)k;
                zv[k] = (czp >= zlo && czp < zhi);
                wz[k] = zv[k] ? (1.0f - fabsf(pz - czp)) : 0.0f;
                zi[k] = zv[k] ? (int)(czp - zlo) : 0;
            }
            if (!zv[0] && !zv[1]) continue;
            float fx = floorf(px);
            float wxa[2]; int xia[2]; bool xv[2];
            #pragma unroll
            for (int i = 0; i < 2; i++) {
                float cxp = fx + (float)i;
                xv[i] = (cxp > 0.0f && cxp < 100.0f);
                wxa[i] = xv[i] ? (1.0f - fabsf(px - cxp)) : 0.0f;
                xia[i] = xv[i] ? (int)cxp : 0;
            }
            if (!xv[0] && !xv[1]) continue;
            float sv[NC];
            #pragma unroll
            for (int c = 0; c < NC; c++) sv[c] = semb[(size_t)c * NPX + rem];
            #pragma unroll
            for (int i = 0; i < 2; i++) {
                if (!xv[i]) continue;
                float wxy = wy * wxa[i];
                #pragma unroll
                for (int k = 0; k < 2; k++) {
                    if (!zv[k]) continue;
                    float w3 = wxy * wz[k];
                    if (w3 == 0.0f) continue;
                    float* dst = &chunkbuf[(xia[i] * CZ + zi[k]) * NC];
                    #pragma unroll
                    for (int c = 0; c < NC; c++)
                        atomicAdd(dst + c, w3 * sv[c]);
                }
            }
        }
        __syncthreads();

        // fold rint of this chunk into persistent cat accumulator (owner-exclusive)
        for (int i = tid; i < VRD * NC; i += 256) {
            int x = i / NC, c = i % NC;
            float ssum = 0.0f;
            #pragma unroll
            for (int zc = 0; zc < CZ; zc++)
                ssum += rintf(chunkbuf[(x * CZ + zc) * NC + c]);
            cat[i] += ssum;
        }
        __syncthreads();
    }

    for (int i = tid; i < VRD * NC; i += 256) {
        int c = i / VRD, x = i % VRD;
        float v = fminf(fmaxf(cat[x * NC + c] * 0.2f, 0.0f), 1.0f);
        maps[((size_t)(b * 18 + 2 + c) * VRD + s) * VRD + x] = v;
    }
}

__device__ __forceinline__ void pose_params(const float* __restrict__ pose_obs,
                                            const float* __restrict__ poses_last,
                                            int b, float& ct, float& st,
                                            float& stx, float& sty) {
    const float DEG = 57.29577951308232f;
    float o  = poses_last[b*3+2] / DEG;
    float so = sinf(o), co = cosf(o);
    float yy = poses_last[b*3+1] + pose_obs[b*3+0]*so + pose_obs[b*3+1]*co;
    float xx = poses_last[b*3+0] + pose_obs[b*3+0]*co - pose_obs[b*3+1]*so;
    float tt = poses_last[b*3+2] + pose_obs[b*3+2]*DEG;
    tt = fmodf(tt - 180.0f, 360.0f) + 180.0f;
    tt = fmodf(tt + 180.0f, 360.0f) - 180.0f;
    stx = -((xx*100.0f/5.0f) - 240.0f) / 240.0f;
    sty = -((yy*100.0f/5.0f) - 240.0f) / 240.0f;
    float t = (90.0f - tt) * 0.017453292519943295f;
    ct = cosf(t); st = sinf(t);
}

__global__ __launch_bounds__(64) void pose_kernel(const float* __restrict__ pose_obs,
                                                  const float* __restrict__ poses_last,
                                                  float* __restrict__ out) {
    int b = threadIdx.x;
    if (b >= BS) return;
    const float DEG = 57.29577951308232f;
    float o  = poses_last[b*3+2] / DEG;
    float so = sinf(o), co = cosf(o);
    float yy = poses_last[b*3+1] + pose_obs[b*3+0]*so + pose_obs[b*3+1]*co;
    float xx = poses_last[b*3+0] + pose_obs[b*3+0]*co - pose_obs[b*3+1]*so;
    float tt = poses_last[b*3+2] + pose_obs[b*3+2]*DEG;
    tt = fmodf(tt - 180.0f, 360.0f) + 180.0f;
    tt = fmodf(tt + 180.0f, 360.0f) - 180.0f;
    out[OFF2 + b*3+0] = xx; out[OFF2 + b*3+1] = yy; out[OFF2 + b*3+2] = tt;
    out[OFF3 + b*3+0] = xx; out[OFF3 + b*3+1] = yy; out[OFF3 + b*3+2] = tt;
}

__global__ __launch_bounds__(256) void rotate_kernel(const float* __restrict__ maps,
                                                     const float* __restrict__ pose_obs,
                                                     const float* __restrict__ poses_last,
                                                     float* __restrict__ rot) {
    int idx = blockIdx.x * blockDim.x + threadIdx.x;
    if (idx >= BS * MM * MM) return;
    int b   = idx / (MM * MM);
    int rem = idx % (MM * MM);
    int y   = rem / MM;
    int x   = rem % MM;
    float ct, st, stx, sty;
    pose_params(pose_obs, poses_last, b, ct, st, stx, sty);
    float Xg = -1.0f + (float)x * (2.0f / 479.0f);
    float Yg = -1.0f + (float)y * (2.0f / 479.0f);
    float gx = ct * Xg - st * Yg;
    float gy = st * Xg + ct * Yg;
    float xf = (gx + 1.0f) * 0.5f * 479.0f;
    float yf = (gy + 1.0f) * 0.5f * 479.0f;
    float x0 = floorf(xf), y0 = floorf(yf);
    float fx = xf - x0, fy = yf - y0;
    float cw[4] = {(1.0f - fx) * (1.0f - fy), fx * (1.0f - fy),
                   (1.0f - fx) * fy,          fx * fy};
    float cx[4] = {x0, x0 + 1.0f, x0, x0 + 1.0f};
    float cy[4] = {y0, y0, y0 + 1.0f, y0 + 1.0f};
    float acc[18];
    #pragma unroll
    for (int m = 0; m < 18; m++) acc[m] = 0.0f;
    #pragma unroll
    for (int k = 0; k < 4; k++) {
        float fxk = cx[k], fyk = cy[k];
        if (!(fxk >= 0.0f && fxk <= 479.0f && fyk >= 0.0f && fyk <= 479.0f)) continue;
        int ix = (int)fxk, iy = (int)fyk;
        if (iy < 240 || iy >= 340 || ix < 190 || ix >= 290) continue;
        int mi = iy - 240, mj = ix - 190;
        float w = cw[k];
        const float* mp = maps + (size_t)b * 18 * VRD * VRD + mi * VRD + mj;
        #pragma unroll
        for (int m = 0; m < 18; m++) acc[m] += w * mp[(size_t)m * VRD * VRD];
    }
    size_t obase = ((size_t)b * CHN) * MM * MM + (size_t)y * MM + x;
    rot[obase + (size_t)0 * MM * MM] = acc[0];
    rot[obase + (size_t)1 * MM * MM] = acc[1];
    rot[obase + (size_t)2 * MM * MM] = 0.0f;
    rot[obase + (size_t)3 * MM * MM] = 0.0f;
    #pragma unroll
    for (int m = 2; m < 18; m++)
        rot[obase + (size_t)(m + 2) * MM * MM] = acc[m];
}

__global__ __launch_bounds__(256) void translate_kernel(const float* __restrict__ rot,
                                                        const float* __restrict__ pose_obs,
                                                        const float* __restrict__ poses_last,
                                                        float* __restrict__ tr) {
    int idx = blockIdx.x * blockDim.x + threadIdx.x;
    if (idx >= BS * MM * MM) return;
    int b   = idx / (MM * MM);
    int rem = idx % (MM * MM);
    int y   = rem / MM;
    int x   = rem % MM;
    float ct, st, stx, sty;
    pose_params(pose_obs, poses_last, b, ct, st, stx, sty);
    float Xg = -1.0f + (float)x * (2.0f / 479.0f);
    float Yg = -1.0f + (float)y * (2.0f / 479.0f);
    float xf = (Xg + stx + 1.0f) * 0.5f * 479.0f;
    float yf = (Yg + sty + 1.0f) * 0.5f * 479.0f;
    float x0 = floorf(xf), y0 = floorf(yf);
    float fx = xf - x0, fy = yf - y0;
    float cw[4] = {(1.0f - fx) * (1.0f - fy), fx * (1.0f - fy),
                   (1.0f - fx) * fy,          fx * fy};
    float cxs[4] = {x0, x0 + 1.0f, x0, x0 + 1.0f};
    float cys[4] = {y0, y0, y0 + 1.0f, y0 + 1.0f};
    bool vk[4]; int offk[4];
    #pragma unroll
    for (int k = 0; k < 4; k++) {
        vk[k] = (cxs[k] >= 0.0f && cxs[k] <= 479.0f && cys[k] >= 0.0f && cys[k] <= 479.0f);
        offk[k] = vk[k] ? ((int)cys[k] * MM + (int)cxs[k]) : 0;
    }
    #pragma unroll
    for (int c = 0; c < CHN; c++) {
        const float* rp = rot + ((size_t)b * CHN + c) * MM * MM;
        float v = 0.0f;
        #pragma unroll
        for (int k = 0; k < 4; k++)
            if (vk[k]) v += cw[k] * rp[offk[k]];
        tr[((size_t)b * CHN + c) * MM * MM + (size_t)y * MM + x] = v;
    }
}

__global__ __launch_bounds__(256) void max_kernel(const float* __restrict__ maps_last,
                                                  const float* __restrict__ tr,
                                                  float* __restrict__ mp) {
    int i = blockIdx.x * blockDim.x + threadIdx.x;
    int n4 = BS * CHN * MM * MM / 4;
    if (i >= n4) return;
    float4 a = ((const float4*)maps_last)[i];
    float4 t = ((const float4*)tr)[i];
    float4 r;
    r.x = fmaxf(a.x, t.x);
    r.y = fmaxf(a.y, t.y);
    r.z = fmaxf(a.z, t.z);
    r.w = fmaxf(a.w, t.w);
    ((float4*)mp)[i] = r;
}

extern "C" void kernel_launch(void* const* d_in, const int* in_sizes, int n_in,
                              void* d_out, int out_size, void* d_ws, size_t ws_size,
                              hipStream_t stream) {
    const float* obs         = (const float*)d_in[0];
    const float* pose_obs    = (const float*)d_in[1];
    const float* maps_last   = (const float*)d_in[2];
    const float* poses_last  = (const float*)d_in[3];
    const float* view_angles = (const float*)d_in[4];
    float* out = (float*)d_out;

    float*  maps = out + OFFM;
    float2* rec  = (float2*)(out + OFFR);
    int*    cnt  = (int*)(out + OFFC);

    hipMemsetAsync(cnt, 0, 400 * 16 * sizeof(int), stream);

    const float foc = (float)(320.0 / tan(39.5 * M_PI / 180.0));

    int npix = BS * NPX;
    bin_kernel<<<(npix + 255) / 256, 256, 0, stream>>>(obs, view_angles, cnt, rec, foc);

    dim3 sgrid(VRD, BS);
    slice_v0_kernel<<<sgrid, 256, 0, stream>>>(cnt, rec, view_angles, maps, out + OFF0, foc);
    slice_vc_kernel<<<sgrid, 256, 0, stream>>>(obs, cnt, rec, view_angles, maps, foc);

    pose_kernel<<<1, 64, 0, stream>>>(pose_obs, poses_last, out);

    int nmap = BS * MM * MM;
    rotate_kernel<<<(nmap + 255) / 256, 256, 0, stream>>>(maps, pose_obs, poses_last,
                                                          out + OFF1);
    translate_kernel<<<(nmap + 255) / 256, 256, 0, stream>>>(out + OFF1, pose_obs,
                                                             poses_last, out + OFF4);
    int n4 = BS * CHN * MM * MM / 4;
    max_kernel<<<(n4 + 255) / 256, 256, 0, stream>>>(maps_last, out + OFF4, out + OFF1);
}